// Round 1
// baseline (114.218 us; speedup 1.0000x reference)
//
#include <hip/hip_runtime.h>
#include <hip/hip_bf16.h>

#define E_N 4
#define B_N 64
#define IN_N 4096
#define H_N 4096
#define R_N 512
#define OUT_N 4096
#define TOT_N 8388608  // R*IN + H*R + R*H + OUT*R

typedef float f32x4 __attribute__((ext_vector_type(4)));
typedef short bf16x8 __attribute__((ext_vector_type(8)));

__device__ __forceinline__ unsigned short f2bf_bits(float f) {
    return __builtin_bit_cast(unsigned short, __float2bfloat16(f));
}
__device__ __forceinline__ float bfbits2f(unsigned short u) {
    return __builtin_bit_cast(float, ((unsigned)u) << 16);
}

// C[e,b,n] = sum_k A[e?,b,k] * (W[n,k] + D[e,n,k])
// One block: 256 thr = 4 waves; wave w owns cols [nt*64 + w*16, +16), all 64 rows (4 m-tiles).
// Split-K: block owns K-chunk of K_TOT/KS. Weight operand split hi/lo bf16 for precision.
template<int K_TOT, int N_TOT, int KS, bool A_SHARED, bool RELU>
__global__ __launch_bounds__(256)
void gemm_layer(const float* __restrict__ A, const float* __restrict__ W,
                const float* __restrict__ D, float* __restrict__ Out)
{
    constexpr int KCH = K_TOT / KS;
    constexpr int NT = N_TOT / 64;
    const int bid = blockIdx.x;
    const int ks = bid % KS;
    const int nt = (bid / KS) % NT;
    const int e  = bid / (KS * NT);
    const int tid = threadIdx.x;
    const int l  = tid & 63;
    const int w  = tid >> 6;
    const int lr = l & 15;          // row within fragment
    const int lk = (l >> 4) << 3;   // k-offset within fragment (8-contig per lane)

    const int nrow  = nt * 64 + w * 16 + lr;   // W/delta row == output col
    const int kbase = ks * KCH + lk;
    const float* Wp = W + (size_t)nrow * K_TOT + kbase;
    const float* Dp = D + (size_t)e * TOT_N + (size_t)nrow * K_TOT + kbase;
    const float* Ap = A + (A_SHARED ? (size_t)0 : (size_t)e * B_N * K_TOT)
                        + (size_t)lr * K_TOT + kbase;

    f32x4 acc[4] = {};

    #pragma unroll 4
    for (int kk = 0; kk < KCH; kk += 32) {
        f32x4 w0 = *(const f32x4*)(Wp + kk);
        f32x4 w1 = *(const f32x4*)(Wp + kk + 4);
        f32x4 d0 = *(const f32x4*)(Dp + kk);
        f32x4 d1 = *(const f32x4*)(Dp + kk + 4);
        f32x4 s0 = w0 + d0;
        f32x4 s1 = w1 + d1;
        bf16x8 bhi, blo;
        #pragma unroll
        for (int j = 0; j < 4; ++j) {
            unsigned short h0 = f2bf_bits(s0[j]);
            bhi[j] = (short)h0;
            blo[j] = (short)f2bf_bits(s0[j] - bfbits2f(h0));
            unsigned short h1 = f2bf_bits(s1[j]);
            bhi[j + 4] = (short)h1;
            blo[j + 4] = (short)f2bf_bits(s1[j] - bfbits2f(h1));
        }
        #pragma unroll
        for (int mt = 0; mt < 4; ++mt) {
            const float* ap = Ap + (size_t)(mt * 16) * K_TOT + kk;
            f32x4 a0 = *(const f32x4*)(ap);
            f32x4 a1 = *(const f32x4*)(ap + 4);
            bf16x8 af;
            #pragma unroll
            for (int j = 0; j < 4; ++j) {
                af[j]     = (short)f2bf_bits(a0[j]);
                af[j + 4] = (short)f2bf_bits(a1[j]);
            }
            acc[mt] = __builtin_amdgcn_mfma_f32_16x16x32_bf16(af, bhi, acc[mt], 0, 0, 0);
            acc[mt] = __builtin_amdgcn_mfma_f32_16x16x32_bf16(af, blo, acc[mt], 0, 0, 0);
        }
    }

    // C/D layout: col = l&15 (== nrow), row = (l>>4)*4 + i
    const int rb = (l >> 4) * 4;
    float* op = Out + (size_t)(e * KS + ks) * B_N * N_TOT + nrow;
    #pragma unroll
    for (int mt = 0; mt < 4; ++mt) {
        #pragma unroll
        for (int i = 0; i < 4; ++i) {
            float v = acc[mt][i];
            if (RELU) v = fmaxf(v, 0.0f);
            op[(size_t)(mt * 16 + rb + i) * N_TOT] = v;
        }
    }
}

// H[e,b,n] = sum_ks P[e,ks,b,n]   (f32, deterministic split-K reduce)
template<int KS, int TOTAL>  // TOTAL = E*B*N
__global__ __launch_bounds__(256)
void reduce_ks(const float* __restrict__ P, float* __restrict__ H)
{
    const int t = blockIdx.x * blockDim.x + threadIdx.x;
    const int idx = t * 4;
    constexpr int BN = TOTAL / E_N;
    const int e = idx / BN;
    const int r = idx - e * BN;
    const float* base = P + (size_t)e * KS * BN + r;
    f32x4 s = {};
    #pragma unroll
    for (int k = 0; k < KS; ++k)
        s += *(const f32x4*)(base + (size_t)k * BN);
    *(f32x4*)(H + idx) = s;
}

// out[b,o] = sum_e scores[e] * P[e,b,o]
__global__ __launch_bounds__(256)
void reduce_experts(const float* __restrict__ P, const float* __restrict__ scores,
                    float* __restrict__ out)
{
    const int t = blockIdx.x * blockDim.x + threadIdx.x;
    const int idx = t * 4;  // over B*OUT
    f32x4 acc = {};
    #pragma unroll
    for (int e = 0; e < E_N; ++e) {
        f32x4 v = *(const f32x4*)(P + (size_t)e * (B_N * OUT_N) + idx);
        acc += scores[e] * v;
    }
    *(f32x4*)(out + idx) = acc;
}

extern "C" void kernel_launch(void* const* d_in, const int* in_sizes, int n_in,
                              void* d_out, int out_size, void* d_ws, size_t ws_size,
                              hipStream_t stream)
{
    const float* x      = (const float*)d_in[0];
    const float* scores = (const float*)d_in[1];
    const float* delta  = (const float*)d_in[2];
    const float* W1     = (const float*)d_in[3];
    const float* W2     = (const float*)d_in[4];
    const float* W3     = (const float*)d_in[5];
    const float* W4     = (const float*)d_in[6];
    float* out = (float*)d_out;

    char* ws = (char*)d_ws;
    float* h1 = (float*)(ws);                              // E*B*R f32   (512 KB)
    float* h2 = (float*)(ws + 524288);                     // E*B*H f32   (4 MB)
    float* h3 = (float*)(ws + 524288 + 4194304);           // E*B*R f32   (512 KB)
    float* P  = (float*)(ws + 524288 + 4194304 + 524288);  // partials    (4 MB)

    const float* d1 = delta;
    const float* d2 = d1 + (size_t)R_N * IN_N;
    const float* d3 = d2 + (size_t)H_N * R_N;
    const float* d4 = d3 + (size_t)R_N * H_N;

    // L1: h1[e,b,r] = x @ (W1+d1)^T      K=4096, N=512, split-K=8
    gemm_layer<IN_N, R_N, 8, true, false>
        <<<dim3(E_N * (R_N / 64) * 8), dim3(256), 0, stream>>>(x, W1, d1, P);
    reduce_ks<8, E_N * B_N * R_N>
        <<<dim3(E_N * B_N * R_N / 4 / 256), dim3(256), 0, stream>>>(P, h1);

    // L2: h2 = relu(h1 @ (W2+d2)^T)      K=512, N=4096
    gemm_layer<R_N, H_N, 1, false, true>
        <<<dim3(E_N * (H_N / 64)), dim3(256), 0, stream>>>(h1, W2, d2, h2);

    // L3: h3 = h2 @ (W3+d3)^T            K=4096, N=512, split-K=8
    gemm_layer<H_N, R_N, 8, false, false>
        <<<dim3(E_N * (R_N / 64) * 8), dim3(256), 0, stream>>>(h2, W3, d3, P);
    reduce_ks<8, E_N * B_N * R_N>
        <<<dim3(E_N * B_N * R_N / 4 / 256), dim3(256), 0, stream>>>(P, h3);

    // L4: P[e,b,o] = h3 @ (W4+d4)^T      K=512, N=4096
    gemm_layer<R_N, OUT_N, 1, false, false>
        <<<dim3(E_N * (OUT_N / 64)), dim3(256), 0, stream>>>(h3, W4, d4, P);

    // out = sum_e scores[e] * P[e]
    reduce_experts<<<dim3(B_N * OUT_N / 4 / 256), dim3(256), 0, stream>>>(P, scores, out);
}

// Round 2
// 110.511 us; speedup vs baseline: 1.0335x; 1.0335x over previous
//
#include <hip/hip_runtime.h>
#include <hip/hip_bf16.h>

#define E_N 4
#define B_N 64
#define IN_N 4096
#define H_N 4096
#define R_N 512
#define OUT_N 4096
#define TOT_N 8388608  // R*IN + H*R + R*H + OUT*R

typedef float f32x4 __attribute__((ext_vector_type(4)));
typedef short bf16x8 __attribute__((ext_vector_type(8)));
typedef unsigned short u16x8 __attribute__((ext_vector_type(8)));

__device__ __forceinline__ unsigned short f2bf_bits(float f) {
    return __builtin_bit_cast(unsigned short, __float2bfloat16(f));
}
__device__ __forceinline__ float bfbits2f(unsigned short u) {
    return __builtin_bit_cast(float, ((unsigned)u) << 16);
}

// C[e,b,n] = sum_k A[e?,b,k] * (W[n,k] + D[e,n,k])
// Block: 256 thr = 4 waves, output tile 64 rows x 32 cols.
//   wave w: wn=w&1 (16-col slice), wm=w>>1 (32-row half, 2 m-tiles).
// A is bf16 (pre-converted). Weights split hi/lo bf16 (precision).
// Split-K: KS chunks, f32 partials. KCH = K_TOT/KS = 512 for all layers.
template<int K_TOT, int N_TOT, int KS, bool A_SHARED, bool RELU, bool OUT_BF16>
__global__ __launch_bounds__(256, 2)
void gemm_layer(const __hip_bfloat16* __restrict__ A, const float* __restrict__ W,
                const float* __restrict__ D, float* __restrict__ OutF,
                __hip_bfloat16* __restrict__ OutB)
{
    constexpr int KCH = K_TOT / KS;
    constexpr int NT = N_TOT / 32;
    const int bid = blockIdx.x;
    const int ks = bid % KS;
    const int nt = (bid / KS) % NT;
    const int e  = bid / (KS * NT);
    const int tid = threadIdx.x;
    const int l  = tid & 63;
    const int w  = tid >> 6;
    const int wn = w & 1;
    const int wm = w >> 1;
    const int lr = l & 15;          // row within fragment
    const int lk = (l >> 4) << 3;   // k-offset within fragment (8-contig per lane)

    const int nrow  = nt * 32 + wn * 16 + lr;   // W/delta row == output col
    const int kbase = ks * KCH + lk;
    const float* Wp = W + (size_t)nrow * K_TOT + kbase;
    const float* Dp = D + (size_t)e * TOT_N + (size_t)nrow * K_TOT + kbase;
    const __hip_bfloat16* Ap = A + (A_SHARED ? (size_t)0 : (size_t)e * B_N * K_TOT)
                                 + (size_t)(wm * 32 + lr) * K_TOT + kbase;

    f32x4 acc[2] = {};

    #pragma unroll 4
    for (int kk = 0; kk < KCH; kk += 32) {
        f32x4 w0 = *(const f32x4*)(Wp + kk);
        f32x4 w1 = *(const f32x4*)(Wp + kk + 4);
        f32x4 d0 = *(const f32x4*)(Dp + kk);
        f32x4 d1 = *(const f32x4*)(Dp + kk + 4);
        f32x4 s0 = w0 + d0;
        f32x4 s1 = w1 + d1;
        bf16x8 bhi, blo;
        #pragma unroll
        for (int j = 0; j < 4; ++j) {
            unsigned short h0 = f2bf_bits(s0[j]);
            bhi[j] = (short)h0;
            blo[j] = (short)f2bf_bits(s0[j] - bfbits2f(h0));
            unsigned short h1 = f2bf_bits(s1[j]);
            bhi[j + 4] = (short)h1;
            blo[j + 4] = (short)f2bf_bits(s1[j] - bfbits2f(h1));
        }
        #pragma unroll
        for (int j = 0; j < 2; ++j) {
            bf16x8 af = *(const bf16x8*)(Ap + (size_t)(j * 16) * K_TOT + kk);
            acc[j] = __builtin_amdgcn_mfma_f32_16x16x32_bf16(af, bhi, acc[j], 0, 0, 0);
            acc[j] = __builtin_amdgcn_mfma_f32_16x16x32_bf16(af, blo, acc[j], 0, 0, 0);
        }
    }

    // C/D layout: col = l&15 (== nrow), row(frag) = (l>>4)*4 + i
    const int rb = (l >> 4) * 4;
    #pragma unroll
    for (int j = 0; j < 2; ++j) {
        #pragma unroll
        for (int i = 0; i < 4; ++i) {
            const int row = wm * 32 + j * 16 + rb + i;
            float v = acc[j][i];
            if (RELU) v = fmaxf(v, 0.0f);
            if (OUT_BF16) {
                OutB[(size_t)e * B_N * N_TOT + (size_t)row * N_TOT + nrow] =
                    __float2bfloat16(v);
            } else {
                OutF[(size_t)(e * KS + ks) * B_N * N_TOT + (size_t)row * N_TOT + nrow] = v;
            }
        }
    }
}

// H[e,b,n] = bf16( sum_ks P[e,ks,b,n] )
template<int KS, int TOTAL, int BN>  // TOTAL = E*BN
__global__ __launch_bounds__(256)
void reduce_ks_bf16(const float* __restrict__ P, __hip_bfloat16* __restrict__ H)
{
    const int t = blockIdx.x * blockDim.x + threadIdx.x;
    const int idx = t * 8;
    const int e = idx / BN;
    const int r = idx - e * BN;
    const float* base = P + (size_t)e * KS * BN + r;
    f32x4 s0 = {}, s1 = {};
    #pragma unroll
    for (int k = 0; k < KS; ++k) {
        s0 += *(const f32x4*)(base + (size_t)k * BN);
        s1 += *(const f32x4*)(base + (size_t)k * BN + 4);
    }
    u16x8 o;
    #pragma unroll
    for (int j = 0; j < 4; ++j) {
        o[j]     = f2bf_bits(s0[j]);
        o[j + 4] = f2bf_bits(s1[j]);
    }
    *(u16x8*)(H + idx) = o;
}

// xb = bf16(x)
__global__ __launch_bounds__(256)
void convert_bf16(const float* __restrict__ X, __hip_bfloat16* __restrict__ Xb)
{
    const int t = blockIdx.x * blockDim.x + threadIdx.x;
    const int idx = t * 8;
    f32x4 a0 = *(const f32x4*)(X + idx);
    f32x4 a1 = *(const f32x4*)(X + idx + 4);
    u16x8 o;
    #pragma unroll
    for (int j = 0; j < 4; ++j) {
        o[j]     = f2bf_bits(a0[j]);
        o[j + 4] = f2bf_bits(a1[j]);
    }
    *(u16x8*)(Xb + idx) = o;
}

// out[b,o] = sum_e scores[e] * P[e,b,o]
__global__ __launch_bounds__(256)
void reduce_experts(const float* __restrict__ P, const float* __restrict__ scores,
                    float* __restrict__ out)
{
    const int t = blockIdx.x * blockDim.x + threadIdx.x;
    const int idx = t * 4;  // over B*OUT
    f32x4 acc = {};
    #pragma unroll
    for (int e = 0; e < E_N; ++e) {
        f32x4 v = *(const f32x4*)(P + (size_t)e * (B_N * OUT_N) + idx);
        acc += scores[e] * v;
    }
    *(f32x4*)(out + idx) = acc;
}

extern "C" void kernel_launch(void* const* d_in, const int* in_sizes, int n_in,
                              void* d_out, int out_size, void* d_ws, size_t ws_size,
                              hipStream_t stream)
{
    const float* x      = (const float*)d_in[0];
    const float* scores = (const float*)d_in[1];
    const float* delta  = (const float*)d_in[2];
    const float* W1     = (const float*)d_in[3];
    const float* W2     = (const float*)d_in[4];
    const float* W3     = (const float*)d_in[5];
    const float* W4     = (const float*)d_in[6];
    float* out = (float*)d_out;

    char* ws = (char*)d_ws;
    __hip_bfloat16* xb  = (__hip_bfloat16*)(ws);                    // 512 KB
    __hip_bfloat16* h1b = (__hip_bfloat16*)(ws + 524288);           // 256 KB
    __hip_bfloat16* h2b = (__hip_bfloat16*)(ws + 786432);           // 2 MB
    __hip_bfloat16* h3b = (__hip_bfloat16*)(ws + 2883584);          // 256 KB
    float* P1 = (float*)(ws + 3145728);                             // 4 MB
    float* P3 = (float*)(ws + 7340032);                             // 4 MB
    float* P4 = (float*)(ws + 11534336);                            // 4 MB

    const float* d1 = delta;
    const float* d2 = d1 + (size_t)R_N * IN_N;
    const float* d3 = d2 + (size_t)H_N * R_N;
    const float* d4 = d3 + (size_t)R_N * H_N;

    // x -> bf16
    convert_bf16<<<dim3(B_N * IN_N / 8 / 256), dim3(256), 0, stream>>>(x, xb);

    // L1: P1[e,ks,b,r] partials of x @ (W1+d1)^T   K=4096, N=512, KS=8
    gemm_layer<IN_N, R_N, 8, true, false, false>
        <<<dim3(E_N * (R_N / 32) * 8), dim3(256), 0, stream>>>(xb, W1, d1, P1, nullptr);
    reduce_ks_bf16<8, E_N * B_N * R_N, B_N * R_N>
        <<<dim3(E_N * B_N * R_N / 8 / 256), dim3(256), 0, stream>>>(P1, h1b);

    // L2: h2b = bf16(relu(h1 @ (W2+d2)^T))   K=512, N=4096, direct
    gemm_layer<R_N, H_N, 1, false, true, true>
        <<<dim3(E_N * (H_N / 32)), dim3(256), 0, stream>>>(h1b, W2, d2, nullptr, h2b);

    // L3: P3 partials of h2 @ (W3+d3)^T      K=4096, N=512, KS=8
    gemm_layer<H_N, R_N, 8, false, false, false>
        <<<dim3(E_N * (R_N / 32) * 8), dim3(256), 0, stream>>>(h2b, W3, d3, P3, nullptr);
    reduce_ks_bf16<8, E_N * B_N * R_N, B_N * R_N>
        <<<dim3(E_N * B_N * R_N / 8 / 256), dim3(256), 0, stream>>>(P3, h3b);

    // L4: P4[e,b,o] = h3 @ (W4+d4)^T         K=512, N=4096, direct f32
    gemm_layer<R_N, OUT_N, 1, false, false, false>
        <<<dim3(E_N * (OUT_N / 32)), dim3(256), 0, stream>>>(h3b, W4, d4, P4, nullptr);

    // out = sum_e scores[e] * P4[e]
    reduce_experts<<<dim3(B_N * OUT_N / 4 / 256), dim3(256), 0, stream>>>(P4, scores, out);
}

// Round 3
// 56.674 us; speedup vs baseline: 2.0153x; 1.9499x over previous
//
#include <hip/hip_runtime.h>
#include <hip/hip_bf16.h>

#define E_N 4
#define B_N 64
#define IN_N 4096
#define H_N 4096
#define R_N 512
#define OUT_N 4096
#define TOT_N 8388608  // R*IN + H*R + R*H + OUT*R

typedef float f32x4 __attribute__((ext_vector_type(4)));
typedef short bf16x8 __attribute__((ext_vector_type(8)));
typedef unsigned short u16x8 __attribute__((ext_vector_type(8)));

__device__ __forceinline__ unsigned short f2bf_bits(float f) {
    return __builtin_bit_cast(unsigned short, __float2bfloat16(f));
}
__device__ __forceinline__ float bfbits2f(unsigned short u) {
    return __builtin_bit_cast(float, ((unsigned)u) << 16);
}

// Direct-to-LDS DMA, 16 B per lane. LDS dest is wave-uniform base + lane*16
// (m104); per-lane scatter lives in the GLOBAL address (pre-swizzled source).
__device__ __forceinline__ void stage16(const void* g, void* l) {
    __builtin_amdgcn_global_load_lds(
        (const __attribute__((address_space(1))) void*)g,
        (__attribute__((address_space(3))) void*)l, 16, 0, 0);
}

// C[e,b,n] = sum_k A[e?,b,k] * (W[n,k] + D[e,n,k])
// Block: 256 thr / 4 waves, tile 64 rows x 32 cols, KCH=512 in 8 tiles of KK=64.
// W,D staged f32 -> LDS (global_load_lds w16, source pre-swizzled); A staged bf16.
// Fragment reads XOR-swizzled (row&7)<<4 -> 2-way banks (free). Weight hi/lo bf16.
template<int K_TOT, int N_TOT, int KS, bool A_SHARED, bool RELU, bool OUT_BF16>
__global__ __launch_bounds__(256, 2)
void gemm_layer(const __hip_bfloat16* __restrict__ A, const float* __restrict__ W,
                const float* __restrict__ D, float* __restrict__ OutF,
                __hip_bfloat16* __restrict__ OutB)
{
    constexpr int KCH = K_TOT / KS;      // 512 for every layer
    constexpr int NT = N_TOT / 32;
    constexpr int NTILES = KCH / 64;     // 8
    __shared__ float Wt[32][64];         // 8 KB
    __shared__ float Dt[32][64];         // 8 KB
    __shared__ __hip_bfloat16 At[64][64];// 8 KB

    const int bid = blockIdx.x;
    const int ks = bid % KS;
    const int nt = (bid / KS) % NT;
    const int e  = bid / (KS * NT);
    const int tid = threadIdx.x;
    const int l  = tid & 63;
    const int w  = tid >> 6;
    const int wn = w & 1;
    const int wm = w >> 1;
    const int lr = l & 15;
    const int lk = (l >> 4) << 3;

    const float* Wb = W + (size_t)(nt * 32) * K_TOT + ks * KCH;
    const float* Db = D + (size_t)e * TOT_N + (size_t)(nt * 32) * K_TOT + ks * KCH;
    const __hip_bfloat16* Ab = A + (A_SHARED ? (size_t)0 : (size_t)e * B_N * K_TOT)
                                 + ks * KCH;

    // 24 wave-instr staging chunks of 1 KB: q 0-7 Wt, 8-15 Dt, 16-23 At. 6 per wave.
    const char* gsrc[6];
    char* ldst[6];
    int kstep[6];
    #pragma unroll
    for (int i = 0; i < 6; ++i) {
        const int q = w * 6 + i;
        if (q < 8) {
            const int off = q * 1024 + l * 16;
            const int row = off >> 8;            // 256 B per f32 row of 64
            const int kb  = off & 255;
            const int skb = kb ^ ((row & 7) << 4);
            gsrc[i] = (const char*)(Wb + (size_t)row * K_TOT) + skb;
            ldst[i] = (char*)&Wt[0][0] + q * 1024;
            kstep[i] = 4;
        } else if (q < 16) {
            const int c = q - 8;
            const int off = c * 1024 + l * 16;
            const int row = off >> 8;
            const int kb  = off & 255;
            const int skb = kb ^ ((row & 7) << 4);
            gsrc[i] = (const char*)(Db + (size_t)row * K_TOT) + skb;
            ldst[i] = (char*)&Dt[0][0] + c * 1024;
            kstep[i] = 4;
        } else {
            const int c = q - 16;
            const int off = c * 1024 + l * 16;
            const int row = off >> 7;            // 128 B per bf16 row of 64
            const int kb  = off & 127;
            const int skb = kb ^ ((row & 7) << 4);
            gsrc[i] = (const char*)(Ab + (size_t)row * K_TOT) + skb;
            ldst[i] = (char*)&At[0][0] + c * 1024;
            kstep[i] = 2;
        }
    }

    f32x4 acc[2] = {};
    const int wrow = wn * 16 + lr;
    const int wswz = (wrow & 7) << 4;
    const int arow0 = wm * 32 + lr;
    const int aswz = (arow0 & 7) << 4;   // mf*16 doesn't change &7

    for (int t = 0; t < NTILES; ++t) {
        const int kk = t * 64;
        #pragma unroll
        for (int i = 0; i < 6; ++i)
            stage16(gsrc[i] + kk * kstep[i], ldst[i]);
        __syncthreads();   // compiler drains vmcnt(0) -> staged data visible

        #pragma unroll
        for (int inner = 0; inner < 2; ++inner) {
            const int b0 = (inner * 32 + lk) * 4;
            const char* wrp = (const char*)&Wt[0][0] + wrow * 256;
            const char* drp = (const char*)&Dt[0][0] + wrow * 256;
            f32x4 w0 = *(const f32x4*)(wrp + ((b0)      ^ wswz));
            f32x4 w1 = *(const f32x4*)(wrp + ((b0 + 16) ^ wswz));
            f32x4 d0 = *(const f32x4*)(drp + ((b0)      ^ wswz));
            f32x4 d1 = *(const f32x4*)(drp + ((b0 + 16) ^ wswz));
            f32x4 s0 = w0 + d0;
            f32x4 s1 = w1 + d1;
            bf16x8 bhi, blo;
            #pragma unroll
            for (int j = 0; j < 4; ++j) {
                unsigned short h0 = f2bf_bits(s0[j]);
                bhi[j] = (short)h0;
                blo[j] = (short)f2bf_bits(s0[j] - bfbits2f(h0));
                unsigned short h1 = f2bf_bits(s1[j]);
                bhi[j + 4] = (short)h1;
                blo[j + 4] = (short)f2bf_bits(s1[j] - bfbits2f(h1));
            }
            const int ab = (inner * 32 + lk) * 2;
            #pragma unroll
            for (int mf = 0; mf < 2; ++mf) {
                const int ar = arow0 + mf * 16;
                const char* arp = (const char*)&At[0][0] + ar * 128;
                bf16x8 af = *(const bf16x8*)(arp + (ab ^ aswz));
                acc[mf] = __builtin_amdgcn_mfma_f32_16x16x32_bf16(af, bhi, acc[mf], 0, 0, 0);
                acc[mf] = __builtin_amdgcn_mfma_f32_16x16x32_bf16(af, blo, acc[mf], 0, 0, 0);
            }
        }
        __syncthreads();   // protect LDS before next stage overwrites
    }

    // C/D layout: col = l&15 (== nrow), row(frag) = (l>>4)*4 + i
    const int rb = (l >> 4) * 4;
    const int nrow = nt * 32 + wrow;
    #pragma unroll
    for (int j = 0; j < 2; ++j) {
        #pragma unroll
        for (int i = 0; i < 4; ++i) {
            const int row = wm * 32 + j * 16 + rb + i;
            float v = acc[j][i];
            if (RELU) v = fmaxf(v, 0.0f);
            if (OUT_BF16) {
                OutB[(size_t)e * B_N * N_TOT + (size_t)row * N_TOT + nrow] =
                    __float2bfloat16(v);
            } else {
                OutF[(size_t)(e * KS + ks) * B_N * N_TOT + (size_t)row * N_TOT + nrow] = v;
            }
        }
    }
}

// H[e,b,n] = bf16( sum_ks P[e,ks,b,n] )
template<int KS, int TOTAL, int BN>
__global__ __launch_bounds__(256)
void reduce_ks_bf16(const float* __restrict__ P, __hip_bfloat16* __restrict__ H)
{
    const int t = blockIdx.x * blockDim.x + threadIdx.x;
    const int idx = t * 8;
    const int e = idx / BN;
    const int r = idx - e * BN;
    const float* base = P + (size_t)e * KS * BN + r;
    f32x4 s0 = {}, s1 = {};
    #pragma unroll
    for (int k = 0; k < KS; ++k) {
        s0 += *(const f32x4*)(base + (size_t)k * BN);
        s1 += *(const f32x4*)(base + (size_t)k * BN + 4);
    }
    u16x8 o;
    #pragma unroll
    for (int j = 0; j < 4; ++j) {
        o[j]     = f2bf_bits(s0[j]);
        o[j + 4] = f2bf_bits(s1[j]);
    }
    *(u16x8*)(H + idx) = o;
}

__global__ __launch_bounds__(256)
void convert_bf16(const float* __restrict__ X, __hip_bfloat16* __restrict__ Xb)
{
    const int t = blockIdx.x * blockDim.x + threadIdx.x;
    const int idx = t * 8;
    f32x4 a0 = *(const f32x4*)(X + idx);
    f32x4 a1 = *(const f32x4*)(X + idx + 4);
    u16x8 o;
    #pragma unroll
    for (int j = 0; j < 4; ++j) {
        o[j]     = f2bf_bits(a0[j]);
        o[j + 4] = f2bf_bits(a1[j]);
    }
    *(u16x8*)(Xb + idx) = o;
}

__global__ __launch_bounds__(256)
void reduce_experts(const float* __restrict__ P, const float* __restrict__ scores,
                    float* __restrict__ out)
{
    const int t = blockIdx.x * blockDim.x + threadIdx.x;
    const int idx = t * 4;
    f32x4 acc = {};
    #pragma unroll
    for (int e = 0; e < E_N; ++e) {
        f32x4 v = *(const f32x4*)(P + (size_t)e * (B_N * OUT_N) + idx);
        acc += scores[e] * v;
    }
    *(f32x4*)(out + idx) = acc;
}

extern "C" void kernel_launch(void* const* d_in, const int* in_sizes, int n_in,
                              void* d_out, int out_size, void* d_ws, size_t ws_size,
                              hipStream_t stream)
{
    const float* x      = (const float*)d_in[0];
    const float* scores = (const float*)d_in[1];
    const float* delta  = (const float*)d_in[2];
    const float* W1     = (const float*)d_in[3];
    const float* W2     = (const float*)d_in[4];
    const float* W3     = (const float*)d_in[5];
    const float* W4     = (const float*)d_in[6];
    float* out = (float*)d_out;

    char* ws = (char*)d_ws;
    __hip_bfloat16* xb  = (__hip_bfloat16*)(ws);                    // 512 KB
    __hip_bfloat16* h1b = (__hip_bfloat16*)(ws + 524288);           // 256 KB
    __hip_bfloat16* h2b = (__hip_bfloat16*)(ws + 786432);           // 2 MB
    __hip_bfloat16* h3b = (__hip_bfloat16*)(ws + 2883584);          // 256 KB
    float* P1 = (float*)(ws + 3145728);                             // 4 MB
    float* P3 = (float*)(ws + 7340032);                             // 4 MB
    float* P4 = (float*)(ws + 11534336);                            // 4 MB

    const float* d1 = delta;
    const float* d2 = d1 + (size_t)R_N * IN_N;
    const float* d3 = d2 + (size_t)H_N * R_N;
    const float* d4 = d3 + (size_t)R_N * H_N;

    convert_bf16<<<dim3(B_N * IN_N / 8 / 256), dim3(256), 0, stream>>>(x, xb);

    // L1: K=4096, N=512, KS=8
    gemm_layer<IN_N, R_N, 8, true, false, false>
        <<<dim3(E_N * (R_N / 32) * 8), dim3(256), 0, stream>>>(xb, W1, d1, P1, nullptr);
    reduce_ks_bf16<8, E_N * B_N * R_N, B_N * R_N>
        <<<dim3(E_N * B_N * R_N / 8 / 256), dim3(256), 0, stream>>>(P1, h1b);

    // L2: K=512, N=4096, relu -> bf16
    gemm_layer<R_N, H_N, 1, false, true, true>
        <<<dim3(E_N * (H_N / 32)), dim3(256), 0, stream>>>(h1b, W2, d2, nullptr, h2b);

    // L3: K=4096, N=512, KS=8
    gemm_layer<H_N, R_N, 8, false, false, false>
        <<<dim3(E_N * (R_N / 32) * 8), dim3(256), 0, stream>>>(h2b, W3, d3, P3, nullptr);
    reduce_ks_bf16<8, E_N * B_N * R_N, B_N * R_N>
        <<<dim3(E_N * B_N * R_N / 8 / 256), dim3(256), 0, stream>>>(P3, h3b);

    // L4: K=512, N=4096
    gemm_layer<R_N, OUT_N, 1, false, false, false>
        <<<dim3(E_N * (OUT_N / 32)), dim3(256), 0, stream>>>(h3b, W4, d4, P4, nullptr);

    reduce_experts<<<dim3(B_N * OUT_N / 4 / 256), dim3(256), 0, stream>>>(P4, scores, out);
}